// Round 5
// baseline (217.642 us; speedup 1.0000x reference)
//
#include <hip/hip_runtime.h>

#define IMG_H 512
#define IMG_W 512
#define TILE_H 32
#define ROWS (TILE_H + 10)   // 42 streamed rows per wave-tile

__device__ __forceinline__ int reflect512(int t) {
    t = (t < 0) ? -t : t;
    t = (t > 511) ? 1022 - t : t;
    return t;
}

// 128-thread blocks = 2 independent waves, each owning a 64x32 output tile.
// NO LDS: each lane loads its own 11 horizontal taps straight from global
// (11 per-lane reflected byte-offsets, constant across rows, against a
// per-row SCALAR base -> `global_load_dword v, vOff, s[base]`). The 11x
// overlap between adjacent lanes is served by L1; 22 independent loads per
// row pipeline under one memory latency. Horizontal 11-tap blur of
// {a, b, a^2+b^2, ab}; vertical 11-tap blur from an 11-deep register ring
// (inner unroll-11 => all indices compile-time; outer loop kept ROLLED to
// avoid R4's full-unroll VGPR/I-cache blowup). fp32 -> pure VALU kernel.
__global__ __launch_bounds__(128, 4) void ssim_kernel(
    const float* __restrict__ img1,
    const float* __restrict__ img2,
    float* __restrict__ out)
{
    // gaussian(11, sigma=1.5), L1-normalized (symmetric)
    const float kW[11] = {
        0.00102838f, 0.00759876f, 0.03600078f, 0.10936055f, 0.21300561f,
        0.26601182f, 0.21300561f, 0.10936055f, 0.03600078f, 0.00759876f,
        0.00102838f };
    const float C1 = 0.0001f;  // (0.01*1)^2
    const float C2 = 0.0009f;  // (0.03*1)^2

    const int tid  = threadIdx.x;
    const int wv   = tid >> 6;        // wave id within block (0/1)
    const int lane = tid & 63;
    const int x0 = blockIdx.x * 64;
    // wave-uniform -> force into SGPR so per-row bases stay scalar
    const int y0 = __builtin_amdgcn_readfirstlane(blockIdx.y * 64 + wv * TILE_H);
    const size_t pbase = (size_t)blockIdx.z * (IMG_H * IMG_W);
    const float* __restrict__ p1 = img1 + pbase;
    const float* __restrict__ p2 = img2 + pbase;
    float* __restrict__ po = out + pbase;

    // per-lane reflected x byte-offsets for the 11 taps (row-invariant;
    // handles the x0=0 / x0=448 edge tiles with the same code path)
    int offB[11];
    #pragma unroll
    for (int k = 0; k < 11; ++k)
        offB[k] = reflect512(x0 - 5 + lane + k) * 4;

    // 11-deep register rings for the 4 horizontally-blurred quantities
    float ring1[11], ring2[11], ringSS[11], ringAB[11];
    const int xo = x0 + lane;

    #pragma unroll 1                   // outer loop MUST stay rolled
    for (int so = 0; so < 44; so += 11) {
        #pragma unroll
        for (int r = 0; r < 11; ++r) {
            const int s = so + r;      // so % 11 == 0 -> s % 11 == r
            if (s < ROWS) {
                // ---- per-row scalar bases (gy uniform) ----
                const int gy = reflect512(y0 - 5 + s);
                const char* r1p = (const char*)(p1 + (size_t)gy * IMG_W);
                const char* r2p = (const char*)(p2 + (size_t)gy * IMG_W);

                // ---- 22 independent tap loads (L1-overlapped) ----
                float a[11], b[11];
                #pragma unroll
                for (int k = 0; k < 11; ++k) {
                    a[k] = *(const float*)(r1p + offB[k]);
                    b[k] = *(const float*)(r2p + offB[k]);
                }

                // ---- horizontal 11-tap blur of {a, b, a^2+b^2, ab} ----
                float h1 = 0.f, h2 = 0.f, hss = 0.f, hab = 0.f;
                #pragma unroll
                for (int k = 0; k < 11; ++k) {
                    const float wk = kW[k];
                    const float ta = wk * a[k];
                    const float tb = wk * b[k];
                    h1 += ta;
                    h2 += tb;
                    hss = fmaf(ta, a[k], hss);
                    hss = fmaf(tb, b[k], hss);
                    hab = fmaf(ta, b[k], hab);
                }
                ring1[r] = h1; ring2[r] = h2; ringSS[r] = hss; ringAB[r] = hab;

                // ---- vertical 11-tap blur + SSIM epilogue ----
                if (s >= 10) {
                    float v1 = 0.f, v2 = 0.f, vss = 0.f, vab = 0.f;
                    #pragma unroll
                    for (int d = 0; d < 11; ++d) {
                        const int slot = (r - d + 22) % 11;  // compile-time
                        const float wd = kW[d];              // symmetric
                        v1  = fmaf(wd, ring1[slot],  v1);
                        v2  = fmaf(wd, ring2[slot],  v2);
                        vss = fmaf(wd, ringSS[slot], vss);
                        vab = fmaf(wd, ringAB[slot], vab);
                    }
                    const float mu12 = v1 * v2;
                    const float musq = fmaf(v1, v1, v2 * v2);
                    const float sgsum = vss - musq;          // sig1^2+sig2^2
                    const float sg12  = vab - mu12;          // sigma12
                    const float num = fmaf(2.f, mu12, C1) * fmaf(2.f, sg12, C2);
                    const float den = (musq + C1) * (sgsum + C2);
                    float rden = __builtin_amdgcn_rcpf(den);
                    rden = rden * (2.f - den * rden);        // 1 Newton step
                    const float ssim = num * rden;
                    const float loss = 0.5f * fminf(fmaxf(1.f - ssim, 0.f), 1.f);
                    po[(size_t)(y0 + s - 10) * IMG_W + xo] = loss;
                }
            }
        }
    }
}

extern "C" void kernel_launch(void* const* d_in, const int* in_sizes, int n_in,
                              void* d_out, int out_size, void* d_ws, size_t ws_size,
                              hipStream_t stream) {
    const float* img1 = (const float*)d_in[0];
    const float* img2 = (const float*)d_in[1];
    float* out = (float*)d_out;
    // 8 x 8 x 48 blocks of 128 threads; 2 independent waves/block,
    // each wave one 64x32 tile -> 6144 wave-tiles, 24 waves/CU offered.
    dim3 grid(IMG_W / 64, IMG_H / 64, 48);
    ssim_kernel<<<grid, dim3(128, 1, 1), 0, stream>>>(img1, img2, out);
}